// Round 3
// baseline (198.257 us; speedup 1.0000x reference)
//
#include <hip/hip_runtime.h>

typedef unsigned short u16;
typedef unsigned int u32;
typedef __bf16 bf16x8 __attribute__((ext_vector_type(8)));
typedef float f32x4 __attribute__((ext_vector_type(4)));

__device__ __forceinline__ u16 f2bf(float f) {
  u32 u = __builtin_bit_cast(u32, f);
  u = (u + 0x7FFFu + ((u >> 16) & 1u)) >> 16;
  return (u16)u;
}
__device__ __forceinline__ float bf2f(u16 h) {
  u32 u = ((u32)h) << 16;
  return __builtin_bit_cast(float, u);
}

#define GLD16(gp, lp) __builtin_amdgcn_global_load_lds( \
    (const __attribute__((address_space(1))) u32*)(const void*)(gp), \
    (__attribute__((address_space(3))) u32*)(void*)(lp), 16, 0, 0)
#define SBAR() __builtin_amdgcn_s_barrier()
#define SCHED0() __builtin_amdgcn_sched_barrier(0)

// ---------------------------------------------------------------------------
// fp32 -> bf16 cast (weights)
__global__ __launch_bounds__(256) void cast_f32_bf16(const float* __restrict__ src,
                                                     u16* __restrict__ dst, int n4) {
  int i = blockIdx.x * 256 + threadIdx.x;
  if (i < n4) {
    float4 v = *(const float4*)(src + (size_t)i * 4);
    ushort4 u;
    u.x = f2bf(v.x); u.y = f2bf(v.y); u.z = f2bf(v.z); u.w = f2bf(v.w);
    *(ushort4*)(dst + (size_t)i * 4) = u;
  }
}

// ---------------------------------------------------------------------------
// permute_in: x (B,C,64,64,64) fp32, roll(+4) + window partition -> xw (B*4096, 512) bf16
__global__ __launch_bounds__(256) void permute_in(const float* __restrict__ x,
                                                  u16* __restrict__ xw) {
  __shared__ float lds[128 * 64];
  int t = threadIdx.x;
  int bx = blockIdx.x;                 // jx*16 + jy
  int b = blockIdx.y;
  int jx = bx >> 4, jy = bx & 15;
#pragma unroll
  for (int it = 0; it < 8; ++it) {
    int idx = t + it * 256;
    int row = idx >> 4, z4 = idx & 15;
    int c = row >> 4, qx = (row >> 2) & 3, qy = row & 3;
    int X = (jx * 4 + qx + 60) & 63;
    int Y = (jy * 4 + qy + 60) & 63;
    float4 v = *(const float4*)(x + ((((size_t)(b * 8 + c) * 64 + X) * 64 + Y) * 64 + z4 * 4));
    *(float4*)(lds + row * 64 + ((z4 ^ (row & 7)) << 2)) = v;
  }
  __syncthreads();
#pragma unroll
  for (int it = 0; it < 8; ++it) {
    int idx = t + it * 256;
    int jz = idx >> 7, r = idx & 127;
    int z4r = (jz + 15) & 15;
    float4 v = *(const float4*)(lds + r * 64 + ((z4r ^ (r & 7)) << 2));
    int nw = jx * 256 + jy * 16 + jz;
    ushort4 u;
    u.x = f2bf(v.x); u.y = f2bf(v.y); u.z = f2bf(v.z); u.w = f2bf(v.w);
    *(ushort4*)(xw + (size_t)(b * 4096 + nw) * 512 + r * 4) = u;
  }
}

// ---------------------------------------------------------------------------
// GEMM: C[M,N] = A[M,K] @ W[N,K]^T + bias. 256x256 tile, BK=32, 8 waves (2x4),
// row-major [256][32] LDS tiles (r1-verified staging/read math), 4-deep LDS
// round-robin, counted vmcnt (never drains in steady state), XCD swizzle.
__global__ __launch_bounds__(512, 1) void gemm_bt(const u16* __restrict__ A,
                                                  const u16* __restrict__ W,
                                                  const float* __restrict__ bias,
                                                  u16* __restrict__ C,
                                                  int M, int N, int K, int nbx) {
  __shared__ u16 As[4 * 8192];   // 4 tiles x (256 rows x 32 k)
  __shared__ u16 Bs[4 * 8192];

  // XCD-chunked block swizzle (gridDim.x % 8 == 0 for both call sites)
  int nwg = gridDim.x;
  int cpx = nwg >> 3;
  int wg = (blockIdx.x & 7) * cpx + (blockIdx.x >> 3);
  int by = wg / nbx, bx = wg - by * nbx;
  int m0 = by * 256, n0 = bx * 256;

  int tid = threadIdx.x;
  int w = tid >> 6, l = tid & 63;
  int wr = w >> 2, wc = w & 3;
  int lr = l & 15, lg = l >> 4;

  int nt = K >> 5;  // 16 for K=512

  f32x4 acc[8][4] = {};

  // staging addresses (r1-verified pattern): slot c = w*128 + i*64 + l,
  // row = c>>2, k-offset = (c&3)*8; LDS dest slot = c (wave-uniform base + lane*16B)
  int c0 = w * 128, c1 = w * 128 + 64;
  int rowA0 = (c0 + l) >> 2, rowA1 = (c1 + l) >> 2;
  int k8_0 = ((c0 + l) & 3) * 8, k8_1 = ((c1 + l) & 3) * 8;
  const u16* pA0 = A + (size_t)(m0 + rowA0) * K + k8_0;
  const u16* pA1 = A + (size_t)(m0 + rowA1) * K + k8_1;
  const u16* pB0 = W + (size_t)(n0 + rowA0) * K + k8_0;
  const u16* pB1 = W + (size_t)(n0 + rowA1) * K + k8_1;

  // prologue: stage tiles 0..3
#pragma unroll
  for (int ts = 0; ts < 4; ++ts) {
    int kadd = ts * 32, bsel = ts * 8192;
    GLD16(pA0 + kadd, As + bsel + c0 * 8);
    GLD16(pA1 + kadd, As + bsel + c1 * 8);
    GLD16(pB0 + kadd, Bs + bsel + c0 * 8);
    GLD16(pB1 + kadd, Bs + bsel + c1 * 8);
  }
  asm volatile("s_waitcnt vmcnt(12)" ::: "memory");
  SCHED0(); SBAR(); SCHED0();

  for (int t = 0; t < nt; ++t) {
    const u16* AsT = As + (t & 3) * 8192;
    const u16* BsT = Bs + (t & 3) * 8192;
    bf16x8 a[8], b[4];
#pragma unroll
    for (int m = 0; m < 8; ++m)
      a[m] = *(const bf16x8*)(AsT + (wr * 128 + m * 16 + lr) * 32 + lg * 8);
#pragma unroll
    for (int n = 0; n < 4; ++n)
      b[n] = *(const bf16x8*)(BsT + (wc * 64 + n * 16 + lr) * 32 + lg * 8);
#pragma unroll
    for (int m = 0; m < 8; ++m)
#pragma unroll
      for (int n = 0; n < 4; ++n)
        acc[m][n] = __builtin_amdgcn_mfma_f32_16x16x32_bf16(a[m], b[n], acc[m][n], 0, 0, 0);
    SCHED0();
    SBAR();        // all waves done reading buf[t&3] (reads consumed by MFMAs above)
    SCHED0();
    if (t + 4 < nt) {
      int ts = t + 4;
      int kadd = ts * 32, bsel = (ts & 3) * 8192;
      GLD16(pA0 + kadd, As + bsel + c0 * 8);
      GLD16(pA1 + kadd, As + bsel + c1 * 8);
      GLD16(pB0 + kadd, Bs + bsel + c0 * 8);
      GLD16(pB1 + kadd, Bs + bsel + c1 * 8);
      SCHED0();
      asm volatile("s_waitcnt vmcnt(12)" ::: "memory");   // tile t+1 resident
    } else if (t + 3 < nt) {
      asm volatile("s_waitcnt vmcnt(8)" ::: "memory");
    } else if (t + 2 < nt) {
      asm volatile("s_waitcnt vmcnt(4)" ::: "memory");
    } else if (t + 1 < nt) {
      asm volatile("s_waitcnt vmcnt(0)" ::: "memory");
    }
    SCHED0();
    SBAR();        // tile t+1 visible to all waves
    SCHED0();
  }

  // epilogue
#pragma unroll
  for (int n = 0; n < 4; ++n) {
    int col = n0 + wc * 64 + n * 16 + lr;
    float bv = bias[col];
#pragma unroll
    for (int m = 0; m < 8; ++m) {
      size_t rowb = (size_t)(m0 + wr * 128 + m * 16 + lg * 4);
#pragma unroll
      for (int j = 0; j < 4; ++j)
        C[(rowb + j) * N + col] = f2bf(acc[m][n][j] + bv);
    }
  }
}

// ---------------------------------------------------------------------------
// attention: per (n,h) unit, q,k,v are (8 x 64). One wave per unit.
__global__ __launch_bounds__(256) void attn(const u16* __restrict__ qkv,
                                            u16* __restrict__ o) {
  __shared__ float lds[4][3][8][68];
  int widx = threadIdx.x >> 6, l = threadIdx.x & 63;
  int unit = blockIdx.x * 4 + widx;
  int n = unit >> 3, h = unit & 7;

  int i = l >> 3, seg = l & 7;
  const u16* base = qkv + (size_t)(i * 4096 + n) * 1536 + h * 64 + seg * 8;
#pragma unroll
  for (int tt = 0; tt < 3; ++tt) {
    ushort4 u0 = *(const ushort4*)(base + tt * 512);
    ushort4 u1 = *(const ushort4*)(base + tt * 512 + 4);
    float* dst = &lds[widx][tt][i][seg * 8];
    float4 f0, f1;
    f0.x = bf2f(u0.x); f0.y = bf2f(u0.y); f0.z = bf2f(u0.z); f0.w = bf2f(u0.w);
    f1.x = bf2f(u1.x); f1.y = bf2f(u1.y); f1.z = bf2f(u1.z); f1.w = bf2f(u1.w);
    *(float4*)dst = f0;
    *(float4*)(dst + 4) = f1;
  }
  __syncthreads();

  int j = l & 7;
  const float* q = &lds[widx][0][i][0];
  const float* k = &lds[widx][1][j][0];
  float s = 0.f;
#pragma unroll
  for (int d = 0; d < 64; d += 4) {
    float4 qv = *(const float4*)(q + d);
    float4 kv = *(const float4*)(k + d);
    s += qv.x * kv.x + qv.y * kv.y + qv.z * kv.z + qv.w * kv.w;
  }
  s *= 0.125f;
  float mx = s;
  mx = fmaxf(mx, __shfl_xor(mx, 1));
  mx = fmaxf(mx, __shfl_xor(mx, 2));
  mx = fmaxf(mx, __shfl_xor(mx, 4));
  float p = __expf(s - mx);
  float sum = p;
  sum += __shfl_xor(sum, 1);
  sum += __shfl_xor(sum, 2);
  sum += __shfl_xor(sum, 4);
  p = p / sum;

  float pr[8];
  int lbase = l & 56;
#pragma unroll
  for (int jj = 0; jj < 8; ++jj) pr[jj] = __shfl(p, lbase + jj);

  float oa[8] = {0, 0, 0, 0, 0, 0, 0, 0};
#pragma unroll
  for (int jj = 0; jj < 8; ++jj) {
    const float* v = &lds[widx][2][jj][j * 8];
    float4 va = *(const float4*)(v);
    float4 vb = *(const float4*)(v + 4);
    oa[0] += pr[jj] * va.x; oa[1] += pr[jj] * va.y;
    oa[2] += pr[jj] * va.z; oa[3] += pr[jj] * va.w;
    oa[4] += pr[jj] * vb.x; oa[5] += pr[jj] * vb.y;
    oa[6] += pr[jj] * vb.z; oa[7] += pr[jj] * vb.w;
  }
  u16* dst = o + (size_t)(i * 4096 + n) * 512 + h * 64 + j * 8;
  ushort4 r0, r1;
  r0.x = f2bf(oa[0]); r0.y = f2bf(oa[1]); r0.z = f2bf(oa[2]); r0.w = f2bf(oa[3]);
  r1.x = f2bf(oa[4]); r1.y = f2bf(oa[5]); r1.z = f2bf(oa[6]); r1.w = f2bf(oa[7]);
  *(ushort4*)dst = r0;
  *(ushort4*)(dst + 4) = r1;
}

// ---------------------------------------------------------------------------
// permute_out: o2 (B*4096, 512) bf16 -> out (B,C,64,64,64) fp32
__global__ __launch_bounds__(256) void permute_out(const u16* __restrict__ o2,
                                                   float* __restrict__ out) {
  __shared__ float lds[16 * 516];
  int t = threadIdx.x;
  int bx = blockIdx.x;
  int b = blockIdx.y;
  int ix = bx >> 4, iy = bx & 15;
  int n0 = ix * 256 + iy * 16;
#pragma unroll
  for (int it = 0; it < 8; ++it) {
    int idx = t + it * 256;
    int iz = idx >> 7, fq = idx & 127;
    ushort4 u = *(const ushort4*)(o2 + ((size_t)(b * 4096 + n0 + iz) * 512 + fq * 4));
    float4 v;
    v.x = bf2f(u.x); v.y = bf2f(u.y); v.z = bf2f(u.z); v.w = bf2f(u.w);
    *(float4*)(lds + iz * 516 + fq * 4) = v;
  }
  __syncthreads();
#pragma unroll
  for (int it = 0; it < 8; ++it) {
    int idx = t + it * 256;
    int fidx = idx >> 4, w4 = idx & 15;
    int c = fidx >> 4, px = (fidx >> 2) & 3, py = fidx & 3;
    int W0 = (w4 * 4 + 4) & 63;
    int pz = W0 >> 4, iz0 = W0 & 15;
    int fa = fidx * 4 + pz;
    float4 v;
    v.x = lds[(iz0 + 0) * 516 + fa];
    v.y = lds[(iz0 + 1) * 516 + fa];
    v.z = lds[(iz0 + 2) * 516 + fa];
    v.w = lds[(iz0 + 3) * 516 + fa];
    int uu = (px * 16 + ix + 60) & 63;
    int vv = (py * 16 + iy + 60) & 63;
    *(float4*)(out + ((((size_t)(b * 8 + c) * 64 + uu) * 64 + vv) * 64 + w4 * 4)) = v;
  }
}

// ---------------------------------------------------------------------------
extern "C" void kernel_launch(void* const* d_in, const int* in_sizes, int n_in,
                              void* d_out, int out_size, void* d_ws, size_t ws_size,
                              hipStream_t stream) {
  const float* x     = (const float*)d_in[0];
  const float* w_in  = (const float*)d_in[1];
  const float* b_in  = (const float*)d_in[2];
  const float* w_out = (const float*)d_in[3];
  const float* b_out = (const float*)d_in[4];
  float* out = (float*)d_out;

  char* ws = (char*)d_ws;
  u16* wq  = (u16*)(ws);                      // 1536*512 bf16
  u16* wo  = (u16*)(ws + 1572864);            // 512*512 bf16
  u16* xw  = (u16*)(ws + 2097152);            // 32768*512 bf16 (reused as o)
  u16* qkv = (u16*)(ws + 35651584);           // 32768*1536 bf16
  u16* o2  = (u16*)(ws + 136314880);          // 32768*512 bf16

  cast_f32_bf16<<<768, 256, 0, stream>>>(w_in, wq, 196608);
  cast_f32_bf16<<<256, 256, 0, stream>>>(w_out, wo, 65536);
  permute_in<<<dim3(256, 8), 256, 0, stream>>>(x, xw);
  gemm_bt<<<768, 512, 0, stream>>>(xw, wq, b_in, qkv, 32768, 1536, 512, 6);
  attn<<<8192, 256, 0, stream>>>(qkv, xw);    // o aliases xw
  gemm_bt<<<256, 512, 0, stream>>>(xw, wo, b_out, o2, 32768, 512, 512, 2);
  permute_out<<<dim3(256, 8), 256, 0, stream>>>(o2, out);
}

// Round 4
// 192.635 us; speedup vs baseline: 1.0292x; 1.0292x over previous
//
#include <hip/hip_runtime.h>

typedef unsigned short u16;
typedef unsigned int u32;
typedef __bf16 bf16x8 __attribute__((ext_vector_type(8)));
typedef float f32x4 __attribute__((ext_vector_type(4)));

__device__ __forceinline__ u16 f2bf(float f) {
  u32 u = __builtin_bit_cast(u32, f);
  u = (u + 0x7FFFu + ((u >> 16) & 1u)) >> 16;
  return (u16)u;
}
__device__ __forceinline__ float bf2f(u16 h) {
  u32 u = ((u32)h) << 16;
  return __builtin_bit_cast(float, u);
}

#define GLD16(gp, lp) __builtin_amdgcn_global_load_lds( \
    (const __attribute__((address_space(1))) u32*)(const void*)(gp), \
    (__attribute__((address_space(3))) u32*)(void*)(lp), 16, 0, 0)
#define SBAR() __builtin_amdgcn_s_barrier()
#define SCHED0() __builtin_amdgcn_sched_barrier(0)

// ---------------------------------------------------------------------------
// fp32 -> bf16 cast (weights)
__global__ __launch_bounds__(256) void cast_f32_bf16(const float* __restrict__ src,
                                                     u16* __restrict__ dst, int n4) {
  int i = blockIdx.x * 256 + threadIdx.x;
  if (i < n4) {
    float4 v = *(const float4*)(src + (size_t)i * 4);
    ushort4 u;
    u.x = f2bf(v.x); u.y = f2bf(v.y); u.z = f2bf(v.z); u.w = f2bf(v.w);
    *(ushort4*)(dst + (size_t)i * 4) = u;
  }
}

// ---------------------------------------------------------------------------
// permute_in: x (B,C,64,64,64) fp32, roll(+4) + window partition -> xw (B*4096, 512) bf16
__global__ __launch_bounds__(256) void permute_in(const float* __restrict__ x,
                                                  u16* __restrict__ xw) {
  __shared__ float lds[128 * 64];
  int t = threadIdx.x;
  int bx = blockIdx.x;                 // jx*16 + jy
  int b = blockIdx.y;
  int jx = bx >> 4, jy = bx & 15;
#pragma unroll
  for (int it = 0; it < 8; ++it) {
    int idx = t + it * 256;
    int row = idx >> 4, z4 = idx & 15;
    int c = row >> 4, qx = (row >> 2) & 3, qy = row & 3;
    int X = (jx * 4 + qx + 60) & 63;
    int Y = (jy * 4 + qy + 60) & 63;
    float4 v = *(const float4*)(x + ((((size_t)(b * 8 + c) * 64 + X) * 64 + Y) * 64 + z4 * 4));
    *(float4*)(lds + row * 64 + ((z4 ^ (row & 7)) << 2)) = v;
  }
  __syncthreads();
#pragma unroll
  for (int it = 0; it < 8; ++it) {
    int idx = t + it * 256;
    int jz = idx >> 7, r = idx & 127;
    int z4r = (jz + 15) & 15;
    float4 v = *(const float4*)(lds + r * 64 + ((z4r ^ (r & 7)) << 2));
    int nw = jx * 256 + jy * 16 + jz;
    ushort4 u;
    u.x = f2bf(v.x); u.y = f2bf(v.y); u.z = f2bf(v.z); u.w = f2bf(v.w);
    *(ushort4*)(xw + (size_t)(b * 4096 + nw) * 512 + r * 4) = u;
  }
}

// ---------------------------------------------------------------------------
// GEMM: C[M,N] = A[M,K] @ W[N,K]^T + bias. 256x256 tile, BK=32, 8 waves (2x4),
// row-major [256][32] LDS tiles, 4-deep LDS round-robin, counted vmcnt.
// MFMA operands SWAPPED (b,a) so per-lane acc regs = 4 consecutive C columns
// -> epilogue stores packed ushort4 (8B/lane), full-line HBM writes.
__global__ __launch_bounds__(512, 1) void gemm_bt(const u16* __restrict__ A,
                                                  const u16* __restrict__ W,
                                                  const float* __restrict__ bias,
                                                  u16* __restrict__ C,
                                                  int M, int N, int K, int nbx) {
  __shared__ u16 As[4 * 8192];   // 4 tiles x (256 rows x 32 k)
  __shared__ u16 Bs[4 * 8192];

  // XCD-chunked block swizzle (gridDim.x % 8 == 0 for both call sites)
  int nwg = gridDim.x;
  int cpx = nwg >> 3;
  int wg = (blockIdx.x & 7) * cpx + (blockIdx.x >> 3);
  int by = wg / nbx, bx = wg - by * nbx;
  int m0 = by * 256, n0 = bx * 256;

  int tid = threadIdx.x;
  int w = tid >> 6, l = tid & 63;
  int wr = w >> 2, wc = w & 3;
  int lr = l & 15, lg = l >> 4;

  int nt = K >> 5;  // 16 for K=512

  f32x4 acc[8][4] = {};

  // staging: slot c = w*128 + i*64 + l; row = c>>2, k-off = (c&3)*8
  int c0 = w * 128, c1 = w * 128 + 64;
  int rowA0 = (c0 + l) >> 2, rowA1 = (c1 + l) >> 2;
  int k8_0 = ((c0 + l) & 3) * 8, k8_1 = ((c1 + l) & 3) * 8;
  const u16* pA0 = A + (size_t)(m0 + rowA0) * K + k8_0;
  const u16* pA1 = A + (size_t)(m0 + rowA1) * K + k8_1;
  const u16* pB0 = W + (size_t)(n0 + rowA0) * K + k8_0;
  const u16* pB1 = W + (size_t)(n0 + rowA1) * K + k8_1;

  // prologue: stage tiles 0..3
#pragma unroll
  for (int ts = 0; ts < 4; ++ts) {
    int kadd = ts * 32, bsel = ts * 8192;
    GLD16(pA0 + kadd, As + bsel + c0 * 8);
    GLD16(pA1 + kadd, As + bsel + c1 * 8);
    GLD16(pB0 + kadd, Bs + bsel + c0 * 8);
    GLD16(pB1 + kadd, Bs + bsel + c1 * 8);
  }
  asm volatile("s_waitcnt vmcnt(12)" ::: "memory");
  SCHED0(); SBAR(); SCHED0();

  for (int t = 0; t < nt; ++t) {
    const u16* AsT = As + (t & 3) * 8192;
    const u16* BsT = Bs + (t & 3) * 8192;
    bf16x8 a[8], b[4];
#pragma unroll
    for (int m = 0; m < 8; ++m)
      a[m] = *(const bf16x8*)(AsT + (wr * 128 + m * 16 + lr) * 32 + lg * 8);
#pragma unroll
    for (int n = 0; n < 4; ++n)
      b[n] = *(const bf16x8*)(BsT + (wc * 64 + n * 16 + lr) * 32 + lg * 8);
#pragma unroll
    for (int m = 0; m < 8; ++m)
#pragma unroll
      for (int n = 0; n < 4; ++n)
        acc[m][n] = __builtin_amdgcn_mfma_f32_16x16x32_bf16(b[n], a[m], acc[m][n], 0, 0, 0);
    SCHED0();
    SBAR();        // all waves done reading buf[t&3]
    SCHED0();
    if (t + 4 < nt) {
      int ts = t + 4;
      int kadd = ts * 32, bsel = (ts & 3) * 8192;
      GLD16(pA0 + kadd, As + bsel + c0 * 8);
      GLD16(pA1 + kadd, As + bsel + c1 * 8);
      GLD16(pB0 + kadd, Bs + bsel + c0 * 8);
      GLD16(pB1 + kadd, Bs + bsel + c1 * 8);
      SCHED0();
      asm volatile("s_waitcnt vmcnt(12)" ::: "memory");   // tile t+1 resident
    } else if (t + 3 < nt) {
      asm volatile("s_waitcnt vmcnt(8)" ::: "memory");
    } else if (t + 2 < nt) {
      asm volatile("s_waitcnt vmcnt(4)" ::: "memory");
    } else if (t + 1 < nt) {
      asm volatile("s_waitcnt vmcnt(0)" ::: "memory");
    }
    SCHED0();
    SBAR();        // tile t+1 visible to all waves
    SCHED0();
  }

  // epilogue: swapped layout -> lane holds C[m0+wr*128+m*16+lr][col0 .. col0+4)
#pragma unroll
  for (int n = 0; n < 4; ++n) {
    int col0 = n0 + wc * 64 + n * 16 + lg * 4;
    float4 bv = *(const float4*)(bias + col0);
#pragma unroll
    for (int m = 0; m < 8; ++m) {
      size_t row = (size_t)(m0 + wr * 128 + m * 16 + lr);
      ushort4 u;
      u.x = f2bf(acc[m][n][0] + bv.x);
      u.y = f2bf(acc[m][n][1] + bv.y);
      u.z = f2bf(acc[m][n][2] + bv.z);
      u.w = f2bf(acc[m][n][3] + bv.w);
      *(ushort4*)(C + row * N + col0) = u;
    }
  }
}

// ---------------------------------------------------------------------------
// attention: per (n,h) unit, q,k,v are (8 x 64). One wave per unit.
__global__ __launch_bounds__(256) void attn(const u16* __restrict__ qkv,
                                            u16* __restrict__ o) {
  __shared__ float lds[4][3][8][68];
  int widx = threadIdx.x >> 6, l = threadIdx.x & 63;
  int unit = blockIdx.x * 4 + widx;
  int n = unit >> 3, h = unit & 7;

  int i = l >> 3, seg = l & 7;
  const u16* base = qkv + (size_t)(i * 4096 + n) * 1536 + h * 64 + seg * 8;
#pragma unroll
  for (int tt = 0; tt < 3; ++tt) {
    ushort4 u0 = *(const ushort4*)(base + tt * 512);
    ushort4 u1 = *(const ushort4*)(base + tt * 512 + 4);
    float* dst = &lds[widx][tt][i][seg * 8];
    float4 f0, f1;
    f0.x = bf2f(u0.x); f0.y = bf2f(u0.y); f0.z = bf2f(u0.z); f0.w = bf2f(u0.w);
    f1.x = bf2f(u1.x); f1.y = bf2f(u1.y); f1.z = bf2f(u1.z); f1.w = bf2f(u1.w);
    *(float4*)dst = f0;
    *(float4*)(dst + 4) = f1;
  }
  __syncthreads();

  int j = l & 7;
  const float* q = &lds[widx][0][i][0];
  const float* k = &lds[widx][1][j][0];
  float s = 0.f;
#pragma unroll
  for (int d = 0; d < 64; d += 4) {
    float4 qv = *(const float4*)(q + d);
    float4 kv = *(const float4*)(k + d);
    s += qv.x * kv.x + qv.y * kv.y + qv.z * kv.z + qv.w * kv.w;
  }
  s *= 0.125f;
  float mx = s;
  mx = fmaxf(mx, __shfl_xor(mx, 1));
  mx = fmaxf(mx, __shfl_xor(mx, 2));
  mx = fmaxf(mx, __shfl_xor(mx, 4));
  float p = __expf(s - mx);
  float sum = p;
  sum += __shfl_xor(sum, 1);
  sum += __shfl_xor(sum, 2);
  sum += __shfl_xor(sum, 4);
  p = p / sum;

  float pr[8];
  int lbase = l & 56;
#pragma unroll
  for (int jj = 0; jj < 8; ++jj) pr[jj] = __shfl(p, lbase + jj);

  float oa[8] = {0, 0, 0, 0, 0, 0, 0, 0};
#pragma unroll
  for (int jj = 0; jj < 8; ++jj) {
    const float* v = &lds[widx][2][jj][j * 8];
    float4 va = *(const float4*)(v);
    float4 vb = *(const float4*)(v + 4);
    oa[0] += pr[jj] * va.x; oa[1] += pr[jj] * va.y;
    oa[2] += pr[jj] * va.z; oa[3] += pr[jj] * va.w;
    oa[4] += pr[jj] * vb.x; oa[5] += pr[jj] * vb.y;
    oa[6] += pr[jj] * vb.z; oa[7] += pr[jj] * vb.w;
  }
  u16* dst = o + (size_t)(i * 4096 + n) * 512 + h * 64 + j * 8;
  ushort4 r0, r1;
  r0.x = f2bf(oa[0]); r0.y = f2bf(oa[1]); r0.z = f2bf(oa[2]); r0.w = f2bf(oa[3]);
  r1.x = f2bf(oa[4]); r1.y = f2bf(oa[5]); r1.z = f2bf(oa[6]); r1.w = f2bf(oa[7]);
  *(ushort4*)dst = r0;
  *(ushort4*)(dst + 4) = r1;
}

// ---------------------------------------------------------------------------
// permute_out: o2 (B*4096, 512) bf16 -> out (B,C,64,64,64) fp32
__global__ __launch_bounds__(256) void permute_out(const u16* __restrict__ o2,
                                                   float* __restrict__ out) {
  __shared__ float lds[16 * 516];
  int t = threadIdx.x;
  int bx = blockIdx.x;
  int b = blockIdx.y;
  int ix = bx >> 4, iy = bx & 15;
  int n0 = ix * 256 + iy * 16;
#pragma unroll
  for (int it = 0; it < 8; ++it) {
    int idx = t + it * 256;
    int iz = idx >> 7, fq = idx & 127;
    ushort4 u = *(const ushort4*)(o2 + ((size_t)(b * 4096 + n0 + iz) * 512 + fq * 4));
    float4 v;
    v.x = bf2f(u.x); v.y = bf2f(u.y); v.z = bf2f(u.z); v.w = bf2f(u.w);
    *(float4*)(lds + iz * 516 + fq * 4) = v;
  }
  __syncthreads();
#pragma unroll
  for (int it = 0; it < 8; ++it) {
    int idx = t + it * 256;
    int fidx = idx >> 4, w4 = idx & 15;
    int c = fidx >> 4, px = (fidx >> 2) & 3, py = fidx & 3;
    int W0 = (w4 * 4 + 4) & 63;
    int pz = W0 >> 4, iz0 = W0 & 15;
    int fa = fidx * 4 + pz;
    float4 v;
    v.x = lds[(iz0 + 0) * 516 + fa];
    v.y = lds[(iz0 + 1) * 516 + fa];
    v.z = lds[(iz0 + 2) * 516 + fa];
    v.w = lds[(iz0 + 3) * 516 + fa];
    int uu = (px * 16 + ix + 60) & 63;
    int vv = (py * 16 + iy + 60) & 63;
    *(float4*)(out + ((((size_t)(b * 8 + c) * 64 + uu) * 64 + vv) * 64 + w4 * 4)) = v;
  }
}

// ---------------------------------------------------------------------------
extern "C" void kernel_launch(void* const* d_in, const int* in_sizes, int n_in,
                              void* d_out, int out_size, void* d_ws, size_t ws_size,
                              hipStream_t stream) {
  const float* x     = (const float*)d_in[0];
  const float* w_in  = (const float*)d_in[1];
  const float* b_in  = (const float*)d_in[2];
  const float* w_out = (const float*)d_in[3];
  const float* b_out = (const float*)d_in[4];
  float* out = (float*)d_out;

  char* ws = (char*)d_ws;
  u16* wq  = (u16*)(ws);                      // 1536*512 bf16
  u16* wo  = (u16*)(ws + 1572864);            // 512*512 bf16
  u16* xw  = (u16*)(ws + 2097152);            // 32768*512 bf16 (reused as o)
  u16* qkv = (u16*)(ws + 35651584);           // 32768*1536 bf16
  u16* o2  = (u16*)(ws + 136314880);          // 32768*512 bf16

  cast_f32_bf16<<<768, 256, 0, stream>>>(w_in, wq, 196608);
  cast_f32_bf16<<<256, 256, 0, stream>>>(w_out, wo, 65536);
  permute_in<<<dim3(256, 8), 256, 0, stream>>>(x, xw);
  gemm_bt<<<768, 512, 0, stream>>>(xw, wq, b_in, qkv, 32768, 1536, 512, 6);
  attn<<<8192, 256, 0, stream>>>(qkv, xw);    // o aliases xw
  gemm_bt<<<256, 512, 0, stream>>>(xw, wo, b_out, o2, 32768, 512, 512, 2);
  permute_out<<<dim3(256, 8), 256, 0, stream>>>(o2, out);
}

// Round 5
// 150.063 us; speedup vs baseline: 1.3212x; 1.2837x over previous
//
#include <hip/hip_runtime.h>

typedef unsigned short u16;
typedef unsigned int u32;
typedef __bf16 bf16x8 __attribute__((ext_vector_type(8)));
typedef float f32x4 __attribute__((ext_vector_type(4)));
typedef unsigned short u16x8 __attribute__((ext_vector_type(8)));

__device__ __forceinline__ u16 f2bf(float f) {
  u32 u = __builtin_bit_cast(u32, f);
  u = (u + 0x7FFFu + ((u >> 16) & 1u)) >> 16;
  return (u16)u;
}
__device__ __forceinline__ float bf2f(u16 h) {
  u32 u = ((u32)h) << 16;
  return __builtin_bit_cast(float, u);
}

#define GLD16(gp, lp) __builtin_amdgcn_global_load_lds( \
    (const __attribute__((address_space(1))) u32*)(const void*)(gp), \
    (__attribute__((address_space(3))) u32*)(void*)(lp), 16, 0, 0)
#define SBAR() __builtin_amdgcn_s_barrier()
#define SCHED0() __builtin_amdgcn_sched_barrier(0)

// ---------------------------------------------------------------------------
__global__ __launch_bounds__(256) void cast_f32_bf16(const float* __restrict__ src,
                                                     u16* __restrict__ dst, int n4) {
  int i = blockIdx.x * 256 + threadIdx.x;
  if (i < n4) {
    float4 v = *(const float4*)(src + (size_t)i * 4);
    ushort4 u;
    u.x = f2bf(v.x); u.y = f2bf(v.y); u.z = f2bf(v.z); u.w = f2bf(v.w);
    *(ushort4*)(dst + (size_t)i * 4) = u;
  }
}

// ---------------------------------------------------------------------------
// permute_in: x (B,C,64,64,64) fp32 -> xw2 rows n-major: row = nw*8 + b, col e
__global__ __launch_bounds__(256) void permute_in(const float* __restrict__ x,
                                                  u16* __restrict__ xw) {
  __shared__ float lds[128 * 64];
  int t = threadIdx.x;
  int bx = blockIdx.x;                 // jx*16 + jy
  int b = blockIdx.y;
  int jx = bx >> 4, jy = bx & 15;
#pragma unroll
  for (int it = 0; it < 8; ++it) {
    int idx = t + it * 256;
    int row = idx >> 4, z4 = idx & 15;
    int c = row >> 4, qx = (row >> 2) & 3, qy = row & 3;
    int X = (jx * 4 + qx + 60) & 63;
    int Y = (jy * 4 + qy + 60) & 63;
    float4 v = *(const float4*)(x + ((((size_t)(b * 8 + c) * 64 + X) * 64 + Y) * 64 + z4 * 4));
    *(float4*)(lds + row * 64 + ((z4 ^ (row & 7)) << 2)) = v;
  }
  __syncthreads();
#pragma unroll
  for (int it = 0; it < 8; ++it) {
    int idx = t + it * 256;
    int jz = idx >> 7, r = idx & 127;
    int z4r = (jz + 15) & 15;
    float4 v = *(const float4*)(lds + r * 64 + ((z4r ^ (r & 7)) << 2));
    int nw = jx * 256 + jy * 16 + jz;
    ushort4 u;
    u.x = f2bf(v.x); u.y = f2bf(v.y); u.z = f2bf(v.z); u.w = f2bf(v.w);
    *(ushort4*)(xw + (size_t)(nw * 8 + b) * 512 + r * 4) = u;
  }
}

// ---------------------------------------------------------------------------
// Fused QKV GEMM + attention. Block = (m-block mb of 256 rows [32 windows x 8],
// head h). GEMM: 256x192 (cols = Q|K|V of head h), K=512, BK=32, 2-phase
// double-buffer (T3 minimal recipe). Epilogue: C+bias -> LDS ctile (bf16),
// in-block softmax over 8x8 per window, PV, write 256x64 attention output.
__global__ __launch_bounds__(512, 1) void gemm_qkv_attn(const u16* __restrict__ A,
                                                        const u16* __restrict__ W,
                                                        const float* __restrict__ bias,
                                                        u16* __restrict__ O) {
  __shared__ u16 smem[51200];     // 102400 B; staging (57344 B) aliased with ctile
  u16* As = smem;                 // 2 x 8192 elems (256 rows x 32 k per tile)
  u16* Bs = smem + 16384;         // 2 x 6144 elems (192 rows x 32 k per tile)

  int cpx = gridDim.x >> 3;       // 1024/8 = 128
  int wg = (blockIdx.x & 7) * cpx + (blockIdx.x >> 3);
  int mb = wg >> 3, h = wg & 7;
  int m0 = mb * 256;

  int tid = threadIdx.x;
  int w = tid >> 6, l = tid & 63;
  int wr = w >> 2, wc = w & 3;
  int lr = l & 15, lg = l >> 4;

  // A staging: 1024 slots, wave w owns [w*128, w*128+128)
  int cA0 = w * 128 + l, cA1 = cA0 + 64;
  const u16* pA0 = A + (size_t)(m0 + (cA0 >> 2)) * 512 + (cA0 & 3) * 8;
  const u16* pA1 = A + (size_t)(m0 + (cA1 >> 2)) * 512 + (cA1 & 3) * 8;
  // B staging: 768 slots (192 rows), wave w owns [w*96, w*96+96)
  int cB0 = w * 96 + l;
  int cB1 = w * 96 + 64 + l;      // valid only for l < 32
  int br0 = cB0 >> 2, br1 = cB1 >> 2;
  const u16* pB0 = W + (size_t)((br0 >> 6) * 512 + h * 64 + (br0 & 63)) * 512 + (cB0 & 3) * 8;
  const u16* pB1 = W + (size_t)((br1 >> 6) * 512 + h * 64 + (br1 & 63)) * 512 + (cB1 & 3) * 8;

  f32x4 acc[8][3] = {};

#define STAGE_QKV(t) { int kadd = (t) * 32, d = (t) & 1;            \
    u16* ad = As + d * 8192 + w * 1024;                             \
    u16* bd = Bs + d * 6144 + w * 768;                              \
    GLD16(pA0 + kadd, ad);                                          \
    GLD16(pA1 + kadd, ad + 512);                                    \
    GLD16(pB0 + kadd, bd);                                          \
    if (l < 32) GLD16(pB1 + kadd, bd + 512); }

  STAGE_QKV(0);
  asm volatile("s_waitcnt vmcnt(0)" ::: "memory");
  SBAR(); SCHED0();

  for (int t = 0; t < 16; ++t) {
    if (t + 1 < 16) STAGE_QKV(t + 1);
    const u16* AsT = As + (t & 1) * 8192;
    const u16* BsT = Bs + (t & 1) * 6144;
    bf16x8 a[8], b[3];
#pragma unroll
    for (int m = 0; m < 8; ++m)
      a[m] = *(const bf16x8*)(AsT + (wr * 128 + m * 16 + lr) * 32 + lg * 8);
#pragma unroll
    for (int n = 0; n < 3; ++n)
      b[n] = *(const bf16x8*)(BsT + (wc * 48 + n * 16 + lr) * 32 + lg * 8);
#pragma unroll
    for (int m = 0; m < 8; ++m)
#pragma unroll
      for (int n = 0; n < 3; ++n)
        acc[m][n] = __builtin_amdgcn_mfma_f32_16x16x32_bf16(b[n], a[m], acc[m][n], 0, 0, 0);
    SCHED0();
    if (t + 1 < 16) asm volatile("s_waitcnt vmcnt(0)" ::: "memory");
    SBAR(); SCHED0();
  }

  // ---- epilogue: C + bias -> ctile (aliases staging; all reads done pre-barrier)
  u16* ct = smem;                 // [256][200] bf16
#pragma unroll
  for (int n = 0; n < 3; ++n) {
    int col0 = wc * 48 + n * 16 + lg * 4;
    int gcol = ((col0 >> 6) << 9) + (h << 6) + (col0 & 63);
    float4 bv = *(const float4*)(bias + gcol);
#pragma unroll
    for (int m = 0; m < 8; ++m) {
      int row = wr * 128 + m * 16 + lr;
      ushort4 uu;
      uu.x = f2bf(acc[m][n][0] + bv.x);
      uu.y = f2bf(acc[m][n][1] + bv.y);
      uu.z = f2bf(acc[m][n][2] + bv.z);
      uu.w = f2bf(acc[m][n][3] + bv.w);
      *(ushort4*)(ct + row * 200 + col0) = uu;
    }
  }
  __syncthreads();

  // ---- attention: 32 windows x 16 threads. thread = (window nw2, i=q-row, jh)
  int nw2 = tid >> 4, u4 = tid & 15, qi = u4 >> 1, jh = u4 & 1;
  const u16* qrow = ct + (nw2 * 8 + qi) * 200;
  float s4[4];
#pragma unroll
  for (int jj = 0; jj < 4; ++jj) {
    const u16* kr = ct + (nw2 * 8 + jh * 4 + jj) * 200 + 64;
    float sacc = 0.f;
#pragma unroll
    for (int dc = 0; dc < 8; ++dc) {
      u16x8 qv = *(const u16x8*)(qrow + dc * 8);
      u16x8 kv = *(const u16x8*)(kr + dc * 8);
#pragma unroll
      for (int e = 0; e < 8; ++e)
        sacc += bf2f((u16)qv[e]) * bf2f((u16)kv[e]);
    }
    s4[jj] = sacc * 0.125f;
  }
  float r0 = __shfl_xor(s4[0], 1), r1 = __shfl_xor(s4[1], 1);
  float r2 = __shfl_xor(s4[2], 1), r3 = __shfl_xor(s4[3], 1);
  float sm[8];
  if (jh == 0) {
    sm[0] = s4[0]; sm[1] = s4[1]; sm[2] = s4[2]; sm[3] = s4[3];
    sm[4] = r0; sm[5] = r1; sm[6] = r2; sm[7] = r3;
  } else {
    sm[0] = r0; sm[1] = r1; sm[2] = r2; sm[3] = r3;
    sm[4] = s4[0]; sm[5] = s4[1]; sm[6] = s4[2]; sm[7] = s4[3];
  }
  float mx = sm[0];
#pragma unroll
  for (int j = 1; j < 8; ++j) mx = fmaxf(mx, sm[j]);
  float p[8], psum = 0.f;
#pragma unroll
  for (int j = 0; j < 8; ++j) { p[j] = __expf(sm[j] - mx); psum += p[j]; }
  float inv = 1.f / psum;

  float ov[32];
#pragma unroll
  for (int e = 0; e < 32; ++e) ov[e] = 0.f;
#pragma unroll
  for (int j = 0; j < 8; ++j) {
    const u16* vr = ct + (nw2 * 8 + j) * 200 + 128 + jh * 32;
    float pj = p[j] * inv;
#pragma unroll
    for (int dc = 0; dc < 4; ++dc) {
      u16x8 vv = *(const u16x8*)(vr + dc * 8);
#pragma unroll
      for (int e = 0; e < 8; ++e)
        ov[dc * 8 + e] += pj * bf2f((u16)vv[e]);
    }
  }
  u32 pk[16];
#pragma unroll
  for (int e = 0; e < 16; ++e)
    pk[e] = (u32)f2bf(ov[2 * e]) | ((u32)f2bf(ov[2 * e + 1]) << 16);
  u32* dst = (u32*)(O + (size_t)(m0 + nw2 * 8 + qi) * 512 + h * 64 + jh * 32);
#pragma unroll
  for (int q4 = 0; q4 < 4; ++q4) {
    uint4 vq; vq.x = pk[q4 * 4]; vq.y = pk[q4 * 4 + 1];
    vq.z = pk[q4 * 4 + 2]; vq.w = pk[q4 * 4 + 3];
    *(uint4*)(dst + q4 * 4) = vq;
  }
}

// ---------------------------------------------------------------------------
// out-proj GEMM: C[32768,512] = o[32768,512] @ wo[512,512]^T + bias.
// 256x256 tile, BK=32, 2-phase double buffer, swapped-operand packed stores.
__global__ __launch_bounds__(512, 1) void gemm_out(const u16* __restrict__ A,
                                                   const u16* __restrict__ W,
                                                   const float* __restrict__ bias,
                                                   u16* __restrict__ C) {
  __shared__ u16 smem[32768];     // A: 2x8192, B: 2x8192 (65536 B)
  u16* As = smem;
  u16* Bs = smem + 16384;

  int cpx = gridDim.x >> 3;       // 256/8 = 32
  int wg = (blockIdx.x & 7) * cpx + (blockIdx.x >> 3);
  int mb = wg >> 1, nb = wg & 1;
  int m0 = mb * 256, n0 = nb * 256;

  int tid = threadIdx.x;
  int w = tid >> 6, l = tid & 63;
  int wr = w >> 2, wc = w & 3;
  int lr = l & 15, lg = l >> 4;

  int cA0 = w * 128 + l, cA1 = cA0 + 64;
  const u16* pA0 = A + (size_t)(m0 + (cA0 >> 2)) * 512 + (cA0 & 3) * 8;
  const u16* pA1 = A + (size_t)(m0 + (cA1 >> 2)) * 512 + (cA1 & 3) * 8;
  const u16* pB0 = W + (size_t)(n0 + (cA0 >> 2)) * 512 + (cA0 & 3) * 8;
  const u16* pB1 = W + (size_t)(n0 + (cA1 >> 2)) * 512 + (cA1 & 3) * 8;

  f32x4 acc[8][4] = {};

#define STAGE_OUT(t) { int kadd = (t) * 32, d = (t) & 1;            \
    u16* ad = As + d * 8192 + w * 1024;                             \
    u16* bd = Bs + d * 8192 + w * 1024;                             \
    GLD16(pA0 + kadd, ad);                                          \
    GLD16(pA1 + kadd, ad + 512);                                    \
    GLD16(pB0 + kadd, bd);                                          \
    GLD16(pB1 + kadd, bd + 512); }

  STAGE_OUT(0);
  asm volatile("s_waitcnt vmcnt(0)" ::: "memory");
  SBAR(); SCHED0();

  for (int t = 0; t < 16; ++t) {
    if (t + 1 < 16) STAGE_OUT(t + 1);
    const u16* AsT = As + (t & 1) * 8192;
    const u16* BsT = Bs + (t & 1) * 8192;
    bf16x8 a[8], b[4];
#pragma unroll
    for (int m = 0; m < 8; ++m)
      a[m] = *(const bf16x8*)(AsT + (wr * 128 + m * 16 + lr) * 32 + lg * 8);
#pragma unroll
    for (int n = 0; n < 4; ++n)
      b[n] = *(const bf16x8*)(BsT + (wc * 64 + n * 16 + lr) * 32 + lg * 8);
#pragma unroll
    for (int m = 0; m < 8; ++m)
#pragma unroll
      for (int n = 0; n < 4; ++n)
        acc[m][n] = __builtin_amdgcn_mfma_f32_16x16x32_bf16(b[n], a[m], acc[m][n], 0, 0, 0);
    SCHED0();
    if (t + 1 < 16) asm volatile("s_waitcnt vmcnt(0)" ::: "memory");
    SBAR(); SCHED0();
  }

#pragma unroll
  for (int n = 0; n < 4; ++n) {
    int col0 = n0 + wc * 64 + n * 16 + lg * 4;
    float4 bv = *(const float4*)(bias + col0);
#pragma unroll
    for (int m = 0; m < 8; ++m) {
      size_t row = (size_t)(m0 + wr * 128 + m * 16 + lr);
      ushort4 uu;
      uu.x = f2bf(acc[m][n][0] + bv.x);
      uu.y = f2bf(acc[m][n][1] + bv.y);
      uu.z = f2bf(acc[m][n][2] + bv.z);
      uu.w = f2bf(acc[m][n][3] + bv.w);
      *(ushort4*)(C + row * 512 + col0) = uu;
    }
  }
}

// ---------------------------------------------------------------------------
// permute_out: o2 rows n-major (row = n*8+b) bf16 -> out (B,C,64,64,64) fp32
__global__ __launch_bounds__(256) void permute_out(const u16* __restrict__ o2,
                                                   float* __restrict__ out) {
  __shared__ float lds[16 * 516];
  int t = threadIdx.x;
  int bx = blockIdx.x;
  int b = blockIdx.y;
  int ix = bx >> 4, iy = bx & 15;
  int n0 = ix * 256 + iy * 16;
#pragma unroll
  for (int it = 0; it < 8; ++it) {
    int idx = t + it * 256;
    int iz = idx >> 7, fq = idx & 127;
    ushort4 u = *(const ushort4*)(o2 + ((size_t)((n0 + iz) * 8 + b) * 512 + fq * 4));
    float4 v;
    v.x = bf2f(u.x); v.y = bf2f(u.y); v.z = bf2f(u.z); v.w = bf2f(u.w);
    *(float4*)(lds + iz * 516 + fq * 4) = v;
  }
  __syncthreads();
#pragma unroll
  for (int it = 0; it < 8; ++it) {
    int idx = t + it * 256;
    int fidx = idx >> 4, w4 = idx & 15;
    int c = fidx >> 4, px = (fidx >> 2) & 3, py = fidx & 3;
    int W0 = (w4 * 4 + 4) & 63;
    int pz = W0 >> 4, iz0 = W0 & 15;
    int fa = fidx * 4 + pz;
    float4 v;
    v.x = lds[(iz0 + 0) * 516 + fa];
    v.y = lds[(iz0 + 1) * 516 + fa];
    v.z = lds[(iz0 + 2) * 516 + fa];
    v.w = lds[(iz0 + 3) * 516 + fa];
    int uu = (px * 16 + ix + 60) & 63;
    int vv = (py * 16 + iy + 60) & 63;
    *(float4*)(out + ((((size_t)(b * 8 + c) * 64 + uu) * 64 + vv) * 64 + w4 * 4)) = v;
  }
}

// ---------------------------------------------------------------------------
extern "C" void kernel_launch(void* const* d_in, const int* in_sizes, int n_in,
                              void* d_out, int out_size, void* d_ws, size_t ws_size,
                              hipStream_t stream) {
  const float* x     = (const float*)d_in[0];
  const float* w_in  = (const float*)d_in[1];
  const float* b_in  = (const float*)d_in[2];
  const float* w_out = (const float*)d_in[3];
  const float* b_out = (const float*)d_in[4];
  float* out = (float*)d_out;

  char* ws = (char*)d_ws;
  u16* wq  = (u16*)(ws);                      // 1536*512 bf16
  u16* wo  = (u16*)(ws + 1572864);            // 512*512 bf16
  u16* xw2 = (u16*)(ws + 2097152);            // 32768*512 bf16, n-major rows
  u16* o   = (u16*)(ws + 35651584);           // 32768*512 bf16 (attn output)
  u16* o2  = (u16*)(ws + 69206016);           // 32768*512 bf16

  cast_f32_bf16<<<768, 256, 0, stream>>>(w_in, wq, 196608);
  cast_f32_bf16<<<256, 256, 0, stream>>>(w_out, wo, 65536);
  permute_in<<<dim3(256, 8), 256, 0, stream>>>(x, xw2);
  gemm_qkv_attn<<<1024, 512, 0, stream>>>(xw2, wq, b_in, o);
  gemm_out<<<256, 512, 0, stream>>>(o, wo, b_out, o2);
  permute_out<<<dim3(256, 8), 256, 0, stream>>>(o2, out);
}

// Round 6
// 144.439 us; speedup vs baseline: 1.3726x; 1.0389x over previous
//
#include <hip/hip_runtime.h>

typedef unsigned short u16;
typedef unsigned int u32;
typedef __bf16 bf16x8 __attribute__((ext_vector_type(8)));
typedef float f32x4 __attribute__((ext_vector_type(4)));
typedef unsigned short u16x8 __attribute__((ext_vector_type(8)));

__device__ __forceinline__ u16 f2bf(float f) {
  u32 u = __builtin_bit_cast(u32, f);
  u = (u + 0x7FFFu + ((u >> 16) & 1u)) >> 16;
  return (u16)u;
}
__device__ __forceinline__ float bf2f(u16 h) {
  u32 u = ((u32)h) << 16;
  return __builtin_bit_cast(float, u);
}

#define GLD16(gp, lp) __builtin_amdgcn_global_load_lds( \
    (const __attribute__((address_space(1))) u32*)(const void*)(gp), \
    (__attribute__((address_space(3))) u32*)(void*)(lp), 16, 0, 0)
#define SBAR() __builtin_amdgcn_s_barrier()
#define SCHED0() __builtin_amdgcn_sched_barrier(0)

// ---------------------------------------------------------------------------
__global__ __launch_bounds__(256) void cast_f32_bf16(const float* __restrict__ src,
                                                     u16* __restrict__ dst, int n4) {
  int i = blockIdx.x * 256 + threadIdx.x;
  if (i < n4) {
    float4 v = *(const float4*)(src + (size_t)i * 4);
    ushort4 u;
    u.x = f2bf(v.x); u.y = f2bf(v.y); u.z = f2bf(v.z); u.w = f2bf(v.w);
    *(ushort4*)(dst + (size_t)i * 4) = u;
  }
}

// ---------------------------------------------------------------------------
// permute_in: x (B,C,64,64,64) fp32 -> xw2 rows n-major: row = nw*8 + b, col e
__global__ __launch_bounds__(256) void permute_in(const float* __restrict__ x,
                                                  u16* __restrict__ xw) {
  __shared__ float lds[128 * 64];
  int t = threadIdx.x;
  int bx = blockIdx.x;                 // jx*16 + jy
  int b = blockIdx.y;
  int jx = bx >> 4, jy = bx & 15;
#pragma unroll
  for (int it = 0; it < 8; ++it) {
    int idx = t + it * 256;
    int row = idx >> 4, z4 = idx & 15;
    int c = row >> 4, qx = (row >> 2) & 3, qy = row & 3;
    int X = (jx * 4 + qx + 60) & 63;
    int Y = (jy * 4 + qy + 60) & 63;
    float4 v = *(const float4*)(x + ((((size_t)(b * 8 + c) * 64 + X) * 64 + Y) * 64 + z4 * 4));
    *(float4*)(lds + row * 64 + ((z4 ^ (row & 7)) << 2)) = v;
  }
  __syncthreads();
#pragma unroll
  for (int it = 0; it < 8; ++it) {
    int idx = t + it * 256;
    int jz = idx >> 7, r = idx & 127;
    int z4r = (jz + 15) & 15;
    float4 v = *(const float4*)(lds + r * 64 + ((z4r ^ (r & 7)) << 2));
    int nw = jx * 256 + jy * 16 + jz;
    ushort4 u;
    u.x = f2bf(v.x); u.y = f2bf(v.y); u.z = f2bf(v.z); u.w = f2bf(v.w);
    *(ushort4*)(xw + (size_t)(nw * 8 + b) * 512 + r * 4) = u;
  }
}

// ---------------------------------------------------------------------------
// Fused QKV GEMM + attention. 256 rows x 192 cols (Q|K|V of one head), K=512.
// BK=64, 8 waves (2x4), 4-phase-per-K-tile schedule: each phase = {ds_read one
// m-pair's A frags || issue ~2 staging loads for t+1 || setprio 12 MFMA}.
// One barrier per K-tile. LDS chunk-XOR swizzle (chunk ^= row&7) applied via
// inverse-permuted global source (linear gld_lds dest) + XOR'd ds_read addr.
__global__ __launch_bounds__(512, 1) void gemm_qkv_attn(const u16* __restrict__ A,
                                                        const u16* __restrict__ W,
                                                        const float* __restrict__ bias,
                                                        u16* __restrict__ O) {
  __shared__ u16 smem[57344];     // 114688 B: As[2][16384] + Bs[2][12288]; ctile aliases
  u16* As = smem;
  u16* Bs = smem + 32768;

  int cpx = gridDim.x >> 3;       // 1024/8 = 128
  int wg = (blockIdx.x & 7) * cpx + (blockIdx.x >> 3);
  int mb = wg >> 3, h = wg & 7;
  int m0 = mb * 256;

  int tid = threadIdx.x;
  int w = tid >> 6, l = tid & 63;
  int wr = w >> 2, wc = w & 3;
  int lr = l & 15, lg = l >> 4;

  // staging sources (per-lane, pre-swizzled): slot s -> row=s>>3, chunk kg=(s&7)^(row&7)
  const u16* pa[4]; int dA[4];
#pragma unroll
  for (int i = 0; i < 4; ++i) {
    int slot = w * 256 + i * 64 + l;
    int row = slot >> 3, kg = (slot & 7) ^ (row & 7);
    pa[i] = A + (size_t)(m0 + row) * 512 + kg * 8;
    dA[i] = (w * 256 + i * 64) * 8;          // wave-uniform LDS elems offset
  }
  const u16* pb[3]; int dB[3];
#pragma unroll
  for (int i = 0; i < 3; ++i) {
    int slot = w * 192 + i * 64 + l;
    int row = slot >> 3, kg = (slot & 7) ^ (row & 7);
    int grow = (row >> 6) * 512 + h * 64 + (row & 63);
    pb[i] = W + (size_t)grow * 512 + kg * 8;
    dB[i] = (w * 192 + i * 64) * 8;
  }

  // fragment read offsets (elems): row*64 + ((kk*4+lg)^(lr&7))*8
  int cx0 = lg ^ (lr & 7), cx1 = cx0 ^ 4;
  int aofs[2] = { (wr * 128 + lr) * 64 + cx0 * 8, (wr * 128 + lr) * 64 + cx1 * 8 };
  int bofs[2] = { (wc * 48 + lr) * 64 + cx0 * 8, (wc * 48 + lr) * 64 + cx1 * 8 };

  f32x4 acc[8][3] = {};

  // prologue: stage tile 0 into slot 0
#pragma unroll
  for (int i = 0; i < 4; ++i) GLD16(pa[i], As + dA[i]);
#pragma unroll
  for (int i = 0; i < 3; ++i) GLD16(pb[i], Bs + dB[i]);
  asm volatile("s_waitcnt vmcnt(0)" ::: "memory");
  SCHED0(); SBAR(); SCHED0();

  for (int t = 0; t < 8; ++t) {
    const u16* AsT = As + (t & 1) * 16384;
    const u16* BsT = Bs + (t & 1) * 12288;
    u16* Ad = As + ((t + 1) & 1) * 16384;
    u16* Bd = Bs + ((t + 1) & 1) * 12288;
    int nx = (t + 1) * 64;
    bool st = (t < 7);
    bf16x8 bfr[3][2];
#pragma unroll
    for (int pg = 0; pg < 4; ++pg) {
      bf16x8 afr[2][2];
#pragma unroll
      for (int mi = 0; mi < 2; ++mi)
#pragma unroll
        for (int kk = 0; kk < 2; ++kk)
          afr[mi][kk] = *(const bf16x8*)(AsT + aofs[kk] + (pg * 2 + mi) * 1024);
      if (pg == 0) {
#pragma unroll
        for (int n = 0; n < 3; ++n)
#pragma unroll
          for (int kk = 0; kk < 2; ++kk)
            bfr[n][kk] = *(const bf16x8*)(BsT + bofs[kk] + n * 1024);
      }
      if (pg == 0 && st) { GLD16(pa[0] + nx, Ad + dA[0]); GLD16(pa[1] + nx, Ad + dA[1]); }
      if (pg == 1 && st) { GLD16(pa[2] + nx, Ad + dA[2]); GLD16(pa[3] + nx, Ad + dA[3]); }
      if (pg == 2 && st) { GLD16(pb[0] + nx, Bd + dB[0]); GLD16(pb[1] + nx, Bd + dB[1]); }
      if (pg == 3 && st) { GLD16(pb[2] + nx, Bd + dB[2]); }
      SCHED0();
      __builtin_amdgcn_s_setprio(1);
#pragma unroll
      for (int mi = 0; mi < 2; ++mi)
#pragma unroll
        for (int n = 0; n < 3; ++n)
#pragma unroll
          for (int kk = 0; kk < 2; ++kk)
            acc[pg * 2 + mi][n] =
                __builtin_amdgcn_mfma_f32_16x16x32_bf16(bfr[n][kk], afr[mi][kk],
                                                        acc[pg * 2 + mi][n], 0, 0, 0);
      __builtin_amdgcn_s_setprio(0);
      SCHED0();
    }
    asm volatile("s_waitcnt vmcnt(0)" ::: "memory");   // t+1 resident (issued >=1-4 phases ago)
    SCHED0(); SBAR(); SCHED0();
  }

  // ---- epilogue: C + bias -> ctile (aliases staging; loop's final SBAR guards)
  u16* ct = smem;                 // [256][200] bf16
#pragma unroll
  for (int n = 0; n < 3; ++n) {
    int col0 = wc * 48 + n * 16 + lg * 4;
    int gcol = ((col0 >> 6) << 9) + (h << 6) + (col0 & 63);
    float4 bv = *(const float4*)(bias + gcol);
#pragma unroll
    for (int m = 0; m < 8; ++m) {
      int row = wr * 128 + m * 16 + lr;
      ushort4 uu;
      uu.x = f2bf(acc[m][n][0] + bv.x);
      uu.y = f2bf(acc[m][n][1] + bv.y);
      uu.z = f2bf(acc[m][n][2] + bv.z);
      uu.w = f2bf(acc[m][n][3] + bv.w);
      *(ushort4*)(ct + row * 200 + col0) = uu;
    }
  }
  __syncthreads();

  // ---- attention: 32 windows x 16 threads. thread = (window nw2, i=q-row, jh)
  int nw2 = tid >> 4, u4 = tid & 15, qi = u4 >> 1, jh = u4 & 1;
  const u16* qrow = ct + (nw2 * 8 + qi) * 200;
  float s4[4];
#pragma unroll
  for (int jj = 0; jj < 4; ++jj) {
    const u16* kr = ct + (nw2 * 8 + jh * 4 + jj) * 200 + 64;
    float sacc = 0.f;
#pragma unroll
    for (int dc = 0; dc < 8; ++dc) {
      u16x8 qv = *(const u16x8*)(qrow + dc * 8);
      u16x8 kv = *(const u16x8*)(kr + dc * 8);
#pragma unroll
      for (int e = 0; e < 8; ++e)
        sacc += bf2f((u16)qv[e]) * bf2f((u16)kv[e]);
    }
    s4[jj] = sacc * 0.125f;
  }
  float r0 = __shfl_xor(s4[0], 1), r1 = __shfl_xor(s4[1], 1);
  float r2 = __shfl_xor(s4[2], 1), r3 = __shfl_xor(s4[3], 1);
  float sm[8];
  if (jh == 0) {
    sm[0] = s4[0]; sm[1] = s4[1]; sm[2] = s4[2]; sm[3] = s4[3];
    sm[4] = r0; sm[5] = r1; sm[6] = r2; sm[7] = r3;
  } else {
    sm[0] = r0; sm[1] = r1; sm[2] = r2; sm[3] = r3;
    sm[4] = s4[0]; sm[5] = s4[1]; sm[6] = s4[2]; sm[7] = s4[3];
  }
  float mx = sm[0];
#pragma unroll
  for (int j = 1; j < 8; ++j) mx = fmaxf(mx, sm[j]);
  float p[8], psum = 0.f;
#pragma unroll
  for (int j = 0; j < 8; ++j) { p[j] = __expf(sm[j] - mx); psum += p[j]; }
  float inv = 1.f / psum;

  float ov[32];
#pragma unroll
  for (int e = 0; e < 32; ++e) ov[e] = 0.f;
#pragma unroll
  for (int j = 0; j < 8; ++j) {
    const u16* vr = ct + (nw2 * 8 + j) * 200 + 128 + jh * 32;
    float pj = p[j] * inv;
#pragma unroll
    for (int dc = 0; dc < 4; ++dc) {
      u16x8 vv = *(const u16x8*)(vr + dc * 8);
#pragma unroll
      for (int e = 0; e < 8; ++e)
        ov[dc * 8 + e] += pj * bf2f((u16)vv[e]);
    }
  }
  u32 pk[16];
#pragma unroll
  for (int e = 0; e < 16; ++e)
    pk[e] = (u32)f2bf(ov[2 * e]) | ((u32)f2bf(ov[2 * e + 1]) << 16);
  u32* dst = (u32*)(O + (size_t)(m0 + nw2 * 8 + qi) * 512 + h * 64 + jh * 32);
#pragma unroll
  for (int q4 = 0; q4 < 4; ++q4) {
    uint4 vq; vq.x = pk[q4 * 4]; vq.y = pk[q4 * 4 + 1];
    vq.z = pk[q4 * 4 + 2]; vq.w = pk[q4 * 4 + 3];
    *(uint4*)(dst + q4 * 4) = vq;
  }
}

// ---------------------------------------------------------------------------
// out-proj GEMM: C[32768,512] = o @ wo^T + bias. 256x256 tile, BK=64,
// same 4-phase schedule + swizzle.
__global__ __launch_bounds__(512, 1) void gemm_out(const u16* __restrict__ A,
                                                   const u16* __restrict__ W,
                                                   const float* __restrict__ bias,
                                                   u16* __restrict__ C) {
  __shared__ u16 smem[65536];     // 131072 B: As[2][16384] + Bs[2][16384]
  u16* As = smem;
  u16* Bs = smem + 32768;

  int cpx = gridDim.x >> 3;       // 256/8 = 32
  int wg = (blockIdx.x & 7) * cpx + (blockIdx.x >> 3);
  int mb = wg >> 1, nb = wg & 1;
  int m0 = mb * 256, n0 = nb * 256;

  int tid = threadIdx.x;
  int w = tid >> 6, l = tid & 63;
  int wr = w >> 2, wc = w & 3;
  int lr = l & 15, lg = l >> 4;

  const u16* pa[4]; const u16* pb[4]; int dS[4];
#pragma unroll
  for (int i = 0; i < 4; ++i) {
    int slot = w * 256 + i * 64 + l;
    int row = slot >> 3, kg = (slot & 7) ^ (row & 7);
    pa[i] = A + (size_t)(m0 + row) * 512 + kg * 8;
    pb[i] = W + (size_t)(n0 + row) * 512 + kg * 8;
    dS[i] = (w * 256 + i * 64) * 8;
  }

  int cx0 = lg ^ (lr & 7), cx1 = cx0 ^ 4;
  int aofs[2] = { (wr * 128 + lr) * 64 + cx0 * 8, (wr * 128 + lr) * 64 + cx1 * 8 };
  int bofs[2] = { (wc * 64 + lr) * 64 + cx0 * 8, (wc * 64 + lr) * 64 + cx1 * 8 };

  f32x4 acc[8][4] = {};

#pragma unroll
  for (int i = 0; i < 4; ++i) GLD16(pa[i], As + dS[i]);
#pragma unroll
  for (int i = 0; i < 4; ++i) GLD16(pb[i], Bs + dS[i]);
  asm volatile("s_waitcnt vmcnt(0)" ::: "memory");
  SCHED0(); SBAR(); SCHED0();

  for (int t = 0; t < 8; ++t) {
    const u16* AsT = As + (t & 1) * 16384;
    const u16* BsT = Bs + (t & 1) * 16384;
    u16* Ad = As + ((t + 1) & 1) * 16384;
    u16* Bd = Bs + ((t + 1) & 1) * 16384;
    int nx = (t + 1) * 64;
    bool st = (t < 7);
    bf16x8 bfr[4][2];
#pragma unroll
    for (int pg = 0; pg < 4; ++pg) {
      bf16x8 afr[2][2];
#pragma unroll
      for (int mi = 0; mi < 2; ++mi)
#pragma unroll
        for (int kk = 0; kk < 2; ++kk)
          afr[mi][kk] = *(const bf16x8*)(AsT + aofs[kk] + (pg * 2 + mi) * 1024);
      if (pg == 0) {
#pragma unroll
        for (int n = 0; n < 4; ++n)
#pragma unroll
          for (int kk = 0; kk < 2; ++kk)
            bfr[n][kk] = *(const bf16x8*)(BsT + bofs[kk] + n * 1024);
      }
      if (pg == 0 && st) { GLD16(pa[0] + nx, Ad + dS[0]); GLD16(pa[1] + nx, Ad + dS[1]); }
      if (pg == 1 && st) { GLD16(pa[2] + nx, Ad + dS[2]); GLD16(pa[3] + nx, Ad + dS[3]); }
      if (pg == 2 && st) { GLD16(pb[0] + nx, Bd + dS[0]); GLD16(pb[1] + nx, Bd + dS[1]); }
      if (pg == 3 && st) { GLD16(pb[2] + nx, Bd + dS[2]); GLD16(pb[3] + nx, Bd + dS[3]); }
      SCHED0();
      __builtin_amdgcn_s_setprio(1);
#pragma unroll
      for (int mi = 0; mi < 2; ++mi)
#pragma unroll
        for (int n = 0; n < 4; ++n)
#pragma unroll
          for (int kk = 0; kk < 2; ++kk)
            acc[pg * 2 + mi][n] =
                __builtin_amdgcn_mfma_f32_16x16x32_bf16(bfr[n][kk], afr[mi][kk],
                                                        acc[pg * 2 + mi][n], 0, 0, 0);
      __builtin_amdgcn_s_setprio(0);
      SCHED0();
    }
    asm volatile("s_waitcnt vmcnt(0)" ::: "memory");
    SCHED0(); SBAR(); SCHED0();
  }

#pragma unroll
  for (int n = 0; n < 4; ++n) {
    int col0 = n0 + wc * 64 + n * 16 + lg * 4;
    float4 bv = *(const float4*)(bias + col0);
#pragma unroll
    for (int m = 0; m < 8; ++m) {
      size_t row = (size_t)(m0 + wr * 128 + m * 16 + lr);
      ushort4 uu;
      uu.x = f2bf(acc[m][n][0] + bv.x);
      uu.y = f2bf(acc[m][n][1] + bv.y);
      uu.z = f2bf(acc[m][n][2] + bv.z);
      uu.w = f2bf(acc[m][n][3] + bv.w);
      *(ushort4*)(C + row * 512 + col0) = uu;
    }
  }
}

// ---------------------------------------------------------------------------
// permute_out: o2 rows n-major (row = n*8+b) bf16 -> out (B,C,64,64,64) fp32
__global__ __launch_bounds__(256) void permute_out(const u16* __restrict__ o2,
                                                   float* __restrict__ out) {
  __shared__ float lds[16 * 516];
  int t = threadIdx.x;
  int bx = blockIdx.x;
  int b = blockIdx.y;
  int ix = bx >> 4, iy = bx & 15;
  int n0 = ix * 256 + iy * 16;
#pragma unroll
  for (int it = 0; it < 8; ++it) {
    int idx = t + it * 256;
    int iz = idx >> 7, fq = idx & 127;
    ushort4 u = *(const ushort4*)(o2 + ((size_t)((n0 + iz) * 8 + b) * 512 + fq * 4));
    float4 v;
    v.x = bf2f(u.x); v.y = bf2f(u.y); v.z = bf2f(u.z); v.w = bf2f(u.w);
    *(float4*)(lds + iz * 516 + fq * 4) = v;
  }
  __syncthreads();
#pragma unroll
  for (int it = 0; it < 8; ++it) {
    int idx = t + it * 256;
    int fidx = idx >> 4, w4 = idx & 15;
    int c = fidx >> 4, px = (fidx >> 2) & 3, py = fidx & 3;
    int W0 = (w4 * 4 + 4) & 63;
    int pz = W0 >> 4, iz0 = W0 & 15;
    int fa = fidx * 4 + pz;
    float4 v;
    v.x = lds[(iz0 + 0) * 516 + fa];
    v.y = lds[(iz0 + 1) * 516 + fa];
    v.z = lds[(iz0 + 2) * 516 + fa];
    v.w = lds[(iz0 + 3) * 516 + fa];
    int uu = (px * 16 + ix + 60) & 63;
    int vv = (py * 16 + iy + 60) & 63;
    *(float4*)(out + ((((size_t)(b * 8 + c) * 64 + uu) * 64 + vv) * 64 + w4 * 4)) = v;
  }
}

// ---------------------------------------------------------------------------
extern "C" void kernel_launch(void* const* d_in, const int* in_sizes, int n_in,
                              void* d_out, int out_size, void* d_ws, size_t ws_size,
                              hipStream_t stream) {
  const float* x     = (const float*)d_in[0];
  const float* w_in  = (const float*)d_in[1];
  const float* b_in  = (const float*)d_in[2];
  const float* w_out = (const float*)d_in[3];
  const float* b_out = (const float*)d_in[4];
  float* out = (float*)d_out;

  char* ws = (char*)d_ws;
  u16* wq  = (u16*)(ws);                      // 1536*512 bf16
  u16* wo  = (u16*)(ws + 1572864);            // 512*512 bf16
  u16* xw2 = (u16*)(ws + 2097152);            // 32768*512 bf16, n-major rows
  u16* o   = (u16*)(ws + 35651584);           // 32768*512 bf16 (attn output)
  u16* o2  = (u16*)(ws + 69206016);           // 32768*512 bf16

  cast_f32_bf16<<<768, 256, 0, stream>>>(w_in, wq, 196608);
  cast_f32_bf16<<<256, 256, 0, stream>>>(w_out, wo, 65536);
  permute_in<<<dim3(256, 8), 256, 0, stream>>>(x, xw2);
  gemm_qkv_attn<<<1024, 512, 0, stream>>>(xw2, wq, b_in, o);
  gemm_out<<<256, 512, 0, stream>>>(o, wo, b_out, o2);
  permute_out<<<dim3(256, 8), 256, 0, stream>>>(o2, out);
}